// Round 8
// baseline (527.882 us; speedup 1.0000x reference)
//
#include <hip/hip_runtime.h>
#include <hip/hip_bf16.h>

#define NB 2
#define NQ 20000
#define DM 64
#define NH 8
#define NL 5
#define NP 4
#define LIN 45109
#define FFN 1024

typedef __attribute__((ext_vector_type(8))) short short8;
typedef __attribute__((ext_vector_type(4))) float f32x4;

// ---- kernel 1: val[row,c] = (dvf_b[row,:] @ Wv + bv)[c], one batch, bf16 out ----
__global__ void val_proj_kernel(const float* __restrict__ dvf_b,
                                const float* __restrict__ Wv,
                                const float* __restrict__ bv,
                                __hip_bfloat16* __restrict__ val) {
    const int lane = threadIdx.x & 63;
    const int row = blockIdx.x * 4 + (threadIdx.x >> 6);
    if (row >= LIN) return;
    float mine = dvf_b[(size_t)row * DM + lane];
    float acc = bv[lane];
#pragma unroll 8
    for (int k = 0; k < DM; k++) {
        float vk = __shfl(mine, k, 64);
        acc = fmaf(vk, Wv[k * DM + lane], acc);
    }
    val[(size_t)row * DM + lane] = __float2bfloat16(acc);
}

// ---- kernel 2: pack W1/W2/[Wo|Wa] to bf16 MFMA B-fragment order ----
// B-frag 16x16x32: lane holds B[k=(lane>>4)*8+j][n=lane&15], j=0..7.
__global__ void pack_kernel(const float* __restrict__ W1, const float* __restrict__ W2,
                            const float* __restrict__ Wo, const float* __restrict__ Wa,
                            __hip_bfloat16* __restrict__ W1p, __hip_bfloat16* __restrict__ W2p,
                            __hip_bfloat16* __restrict__ Woap) {
    const int t = blockIdx.x * 256 + threadIdx.x;
    const int lane = t & 63;
    const int m = lane & 15, qd = lane >> 4;
    const int seg = t >> 6;
    if (seg < 128) {                  // W1 (64x1024): 64 ntiles x 2 kchunks
        const int nt = seg >> 1, kc = seg & 1;
        const int n = nt * 16 + m, kb = kc * 32 + qd * 8;
        __hip_bfloat16* dst = W1p + ((size_t)seg * 64 + lane) * 8;
#pragma unroll
        for (int j = 0; j < 8; j++) dst[j] = __float2bfloat16(W1[(size_t)(kb + j) * FFN + n]);
    } else if (seg < 256) {           // W2 (1024x64): 4 ntiles x 32 kchunks
        const int sl = seg - 128;
        const int nt = sl >> 5, kc = sl & 31;
        const int n = nt * 16 + m, kb = kc * 32 + qd * 8;
        __hip_bfloat16* dst = W2p + ((size_t)sl * 64 + lane) * 8;
#pragma unroll
        for (int j = 0; j < 8; j++) dst[j] = __float2bfloat16(W2[(size_t)(kb + j) * DM + n]);
    } else if (seg < 316) {           // [Wo|Wa] (64x480): 30 ntiles x 2 kchunks
        const int sl = seg - 256;
        const int nt = sl >> 1, kc = sl & 1;
        const int n = nt * 16 + m, kb = kc * 32 + qd * 8;
        __hip_bfloat16* dst = Woap + ((size_t)sl * 64 + lane) * 8;
#pragma unroll
        for (int j = 0; j < 8; j++) {
            const int k = kb + j;
            const float v = (n < 320) ? Wo[(size_t)k * 320 + n] : Wa[(size_t)k * 160 + (n - 320)];
            dst[j] = __float2bfloat16(v);
        }
    }
}

// ---- kernel 3: attn, 16 queries/block; phase B via MFMA; C/D/LN1 f32 ----
__global__ void __launch_bounds__(256)
attn16_kernel(const float* __restrict__ q_feat,
              const float* __restrict__ ref_pts,
              const float* __restrict__ q_pos,
              const __hip_bfloat16* __restrict__ Woap,
              const float* __restrict__ bo, const float* __restrict__ ba,
              const float* __restrict__ Wout, const float* __restrict__ bout,
              const float* __restrict__ g1, const float* __restrict__ b1,
              const __hip_bfloat16* __restrict__ val,
              float* __restrict__ xout) {
    __shared__ __align__(16) __hip_bfloat16 qb[16][72];   // q = qf+qp, A-layout
    __shared__ __align__(16) float offs[16][321];
    __shared__ __align__(16) float aws[16][161];
    __shared__ __align__(16) float outv[16][64];
    __shared__ __align__(16) float refs[16][2];

    const int tid = threadIdx.x;
    const int lane = tid & 63;
    const int w = tid >> 6;
    const int m16 = lane & 15, qd = lane >> 4;
    const int q0 = blockIdx.x * 16;

    const int sz[NL]  = {184, 92, 46, 23, 12};
    const int lsi[NL] = {0, 33856, 42320, 44436, 44965};

    // ---- phase A: wave w owns queries 4w..4w+3 ----
    float qfr[4];
#pragma unroll
    for (int i = 0; i < 4; i++) {
        const int qq = w * 4 + i;
        const float f = q_feat[(size_t)(q0 + qq) * DM + lane];
        const float p = q_pos[(size_t)(q0 + qq) * DM + lane];
        qfr[i] = f;
        qb[qq][lane] = __float2bfloat16(f + p);
    }
    if (tid < 32) refs[tid >> 1][tid & 1] = ref_pts[(size_t)(q0 + (tid >> 1)) * 2 + (tid & 1)];
    __syncthreads();

    // ---- phase B: [offs|aws] = q @ [Wo|Wa] + bias via MFMA ----
    for (int nt = w; nt < 30; nt += 4) {
        f32x4 acc = {0.f, 0.f, 0.f, 0.f};
#pragma unroll
        for (int kc = 0; kc < 2; kc++) {
            const short8 a = *(const short8*)&qb[m16][kc * 32 + qd * 8];
            const short8 b = *(const short8*)(Woap + ((size_t)(nt * 2 + kc) * 64 + lane) * 8);
            acc = __builtin_amdgcn_mfma_f32_16x16x32_bf16(a, b, acc, 0, 0, 0);
        }
        const int n = nt * 16 + m16;
        if (n < 320) {
            const float bn = bo[n];
#pragma unroll
            for (int r = 0; r < 4; r++) offs[qd * 4 + r][n] = acc[r] + bn;
        } else {
            const float bn = ba[n - 320];
#pragma unroll
            for (int r = 0; r < 4; r++) aws[qd * 4 + r][n - 320] = acc[r] + bn;
        }
    }
    __syncthreads();

    // ---- softmax per (query, head) over 20 ----
    if (tid < 128) {
        const int q = tid >> 3, h = tid & 7;
        float* p = &aws[q][h * 20];
        float mx = p[0];
        for (int j = 1; j < 20; j++) mx = fmaxf(mx, p[j]);
        float s = 0.f;
        for (int j = 0; j < 20; j++) { const float e = expf(p[j] - mx); p[j] = e; s += e; }
        const float inv = 1.f / s;
        for (int j = 0; j < 20; j++) p[j] *= inv;
    }
    __syncthreads();

    // ---- phase C: bilinear sampling (wave w: queries 4w..4w+3); lane = h*8+d ----
    {
        const int h = lane >> 3;
        const __hip_bfloat16* vbase = val + lane;
#pragma unroll
        for (int i = 0; i < 4; i++) {
            const int qq = w * 4 + i;
            const float refx = refs[qq][0], refy = refs[qq][1];
            float acc = 0.f;
#pragma unroll
            for (int l = 0; l < NL; l++) {
                const int Wl = sz[l];
                const float Wf = (float)Wl;
                const int st = lsi[l];
#pragma unroll
                for (int p = 0; p < NP; p++) {
                    const int c = ((h * NL + l) * NP + p) * 2;
                    const float ox = offs[qq][c], oy = offs[qq][c + 1];
                    const float fx = (refx + ox / Wf) * Wf - 0.5f;
                    const float fy = (refy + oy / Wf) * Wf - 0.5f;
                    const float x0f = floorf(fx), y0f = floorf(fy);
                    const float wx = fx - x0f, wy = fy - y0f;
                    const int x0 = (int)x0f, y0 = (int)y0f;
                    const float aV = aws[qq][h * 20 + l * NP + p];
                    float s = 0.f;
                    if (x0 >= 0 && x0 < Wl && y0 >= 0 && y0 < Wl)
                        s = fmaf(__bfloat162float(vbase[(size_t)(st + y0 * Wl + x0) * DM]), (1.f - wx) * (1.f - wy), s);
                    if (x0 + 1 >= 0 && x0 + 1 < Wl && y0 >= 0 && y0 < Wl)
                        s = fmaf(__bfloat162float(vbase[(size_t)(st + y0 * Wl + x0 + 1) * DM]), wx * (1.f - wy), s);
                    if (x0 >= 0 && x0 < Wl && y0 + 1 >= 0 && y0 + 1 < Wl)
                        s = fmaf(__bfloat162float(vbase[(size_t)(st + (y0 + 1) * Wl + x0) * DM]), (1.f - wx) * wy, s);
                    if (x0 + 1 >= 0 && x0 + 1 < Wl && y0 + 1 >= 0 && y0 + 1 < Wl)
                        s = fmaf(__bfloat162float(vbase[(size_t)(st + (y0 + 1) * Wl + x0 + 1) * DM]), wx * wy, s);
                    acc = fmaf(aV, s, acc);
                }
            }
            outv[qq][lane] = acc;   // wave-local write, wave-local read below
        }
    }
    // no barrier needed: phase D reads only this wave's outv rows

    // ---- phase D: attn @ Wout + bout; residual; LN1; store x1 (4 queries/wave) ----
    {
        float attn0 = bout[lane], attn1 = attn0, attn2 = attn0, attn3 = attn0;
        const int qb4 = w * 4;
#pragma unroll 8
        for (int k = 0; k < DM; k++) {
            const float wv = Wout[k * DM + lane];
            attn0 = fmaf(outv[qb4 + 0][k], wv, attn0);
            attn1 = fmaf(outv[qb4 + 1][k], wv, attn1);
            attn2 = fmaf(outv[qb4 + 2][k], wv, attn2);
            attn3 = fmaf(outv[qb4 + 3][k], wv, attn3);
        }
        const float g1v = g1[lane], b1v = b1[lane];
        float attn[4] = {attn0, attn1, attn2, attn3};
#pragma unroll
        for (int i = 0; i < 4; i++) {
            const float xpre = qfr[i] + attn[i];
            float s = xpre, s2 = xpre * xpre;
#pragma unroll
            for (int o = 32; o >= 1; o >>= 1) {
                s += __shfl_xor(s, o, 64);
                s2 += __shfl_xor(s2, o, 64);
            }
            const float mean = s * (1.f / 64.f);
            const float var = s2 * (1.f / 64.f) - mean * mean;
            const float xn = (xpre - mean) * rsqrtf(var + 1e-5f);
            xout[(size_t)(q0 + qb4 + i) * DM + lane] = xn * g1v + b1v;
        }
    }
}

// ---- kernel 4: FFN via MFMA, 16 queries/block; in-place on io ----
__global__ void __launch_bounds__(256)
ffn_kernel(const __hip_bfloat16* __restrict__ W1p, const float* __restrict__ bff1,
           const __hip_bfloat16* __restrict__ W2p, const float* __restrict__ bff2,
           const float* __restrict__ g2, const float* __restrict__ b2,
           float* __restrict__ io) {
    __shared__ __align__(16) __hip_bfloat16 xb[16][72];
    __shared__ __align__(16) float xs[16][64];
    __shared__ __align__(16) __hip_bfloat16 hb[16][520];
    __shared__ __align__(16) float yr[16][64];

    const int tid = threadIdx.x;
    const int lane = tid & 63;
    const int w = tid >> 6;
    const int m16 = lane & 15, qd = lane >> 4;
    const int q0 = blockIdx.x * 16;

    {
        const int q = tid >> 4, i = tid & 15;
        const float4 v = *(const float4*)&io[(size_t)(q0 + q) * DM + i * 4];
        *(float4*)&xs[q][i * 4] = v;
        xb[q][i * 4 + 0] = __float2bfloat16(v.x);
        xb[q][i * 4 + 1] = __float2bfloat16(v.y);
        xb[q][i * 4 + 2] = __float2bfloat16(v.z);
        xb[q][i * 4 + 3] = __float2bfloat16(v.w);
    }
    __syncthreads();

    f32x4 yacc = {0.f, 0.f, 0.f, 0.f};
#pragma unroll
    for (int half = 0; half < 2; half++) {
#pragma unroll 2
        for (int ti = 0; ti < 8; ti++) {
            const int nt = half * 32 + w + ti * 4;
            f32x4 acc = {0.f, 0.f, 0.f, 0.f};
#pragma unroll
            for (int kc = 0; kc < 2; kc++) {
                const short8 a = *(const short8*)&xb[m16][kc * 32 + qd * 8];
                const short8 b = *(const short8*)(W1p + ((size_t)(nt * 2 + kc) * 64 + lane) * 8);
                acc = __builtin_amdgcn_mfma_f32_16x16x32_bf16(a, b, acc, 0, 0, 0);
            }
            const int ncol = (nt - half * 32) * 16 + m16;
            const float bn = bff1[nt * 16 + m16];
#pragma unroll
            for (int r = 0; r < 4; r++)
                hb[qd * 4 + r][ncol] = __float2bfloat16(fmaxf(acc[r] + bn, 0.f));
        }
        __syncthreads();
#pragma unroll 4
        for (int kc2 = 0; kc2 < 16; kc2++) {
            const short8 a = *(const short8*)&hb[m16][kc2 * 32 + qd * 8];
            const short8 b = *(const short8*)(W2p + ((size_t)(w * 32 + half * 16 + kc2) * 64 + lane) * 8);
            yacc = __builtin_amdgcn_mfma_f32_16x16x32_bf16(a, b, yacc, 0, 0, 0);
        }
        __syncthreads();
    }

    {
        const int n = w * 16 + m16;
        const float bn = bff2[n];
#pragma unroll
        for (int r = 0; r < 4; r++) {
            const int mm = qd * 4 + r;
            yr[mm][n] = yacc[r] + bn + xs[mm][n];
        }
    }
    __syncthreads();

    {
        const int q = tid >> 4, i = tid & 15;
        const float4 v = *(const float4*)&yr[q][i * 4];
        float s = v.x + v.y + v.z + v.w;
        float s2 = v.x * v.x + v.y * v.y + v.z * v.z + v.w * v.w;
#pragma unroll
        for (int o = 8; o >= 1; o >>= 1) { s += __shfl_xor(s, o, 64); s2 += __shfl_xor(s2, o, 64); }
        const float mean = s * (1.f / 64.f);
        const float var = s2 * (1.f / 64.f) - mean * mean;
        const float rstd = rsqrtf(var + 1e-5f);
        const float4 g = *(const float4*)&g2[i * 4];
        const float4 bb = *(const float4*)&b2[i * 4];
        float4 o;
        o.x = (v.x - mean) * rstd * g.x + bb.x;
        o.y = (v.y - mean) * rstd * g.y + bb.y;
        o.z = (v.z - mean) * rstd * g.z + bb.z;
        o.w = (v.w - mean) * rstd * g.w + bb.w;
        *(float4*)&io[(size_t)(q0 + q) * DM + i * 4] = o;
    }
}

extern "C" void kernel_launch(void* const* d_in, const int* in_sizes, int n_in,
                              void* d_out, int out_size, void* d_ws, size_t ws_size,
                              hipStream_t stream) {
    const int B0 = (in_sizes[4] >= 4096) ? 4 : 6;   // int side-inputs present -> 6
    const float* q_feat = (const float*)d_in[0];
    const float* dvf    = (const float*)d_in[1];
    const float* refp   = (const float*)d_in[2];
    const float* q_pos  = (const float*)d_in[3];
    const float* Wv   = (const float*)d_in[B0 + 0];
    const float* bv   = (const float*)d_in[B0 + 1];
    const float* Wo   = (const float*)d_in[B0 + 2];
    const float* bo   = (const float*)d_in[B0 + 3];
    const float* Wa   = (const float*)d_in[B0 + 4];
    const float* ba   = (const float*)d_in[B0 + 5];
    const float* Wout = (const float*)d_in[B0 + 6];
    const float* bout = (const float*)d_in[B0 + 7];
    const float* g1   = (const float*)d_in[B0 + 8];
    const float* b1   = (const float*)d_in[B0 + 9];
    const float* W1   = (const float*)d_in[B0 + 10];
    const float* bff1 = (const float*)d_in[B0 + 11];
    const float* W2   = (const float*)d_in[B0 + 12];
    const float* bff2 = (const float*)d_in[B0 + 13];
    const float* g2   = (const float*)d_in[B0 + 14];
    const float* b2   = (const float*)d_in[B0 + 15];
    float* out = (float*)d_out;

    const size_t val_elems = (size_t)LIN * DM;
    const size_t pack_elems = (size_t)(128 + 128 + 60) * 64 * 8;   // 161792 bf16
    const bool dbuf = ws_size >= (pack_elems + 2 * val_elems) * sizeof(__hip_bfloat16);

    __hip_bfloat16* W1p = (__hip_bfloat16*)d_ws;
    __hip_bfloat16* W2p = W1p + (size_t)128 * 64 * 8;
    __hip_bfloat16* Woap = W2p + (size_t)128 * 64 * 8;
    __hip_bfloat16* val0 = W1p + pack_elems;
    __hip_bfloat16* val1 = dbuf ? val0 + val_elems : val0;

    pack_kernel<<<79, 256, 0, stream>>>(W1, W2, Wo, Wa, W1p, W2p, Woap);

    if (dbuf) {
        val_proj_kernel<<<(LIN + 3) / 4, 256, 0, stream>>>(dvf, Wv, bv, val0);
        val_proj_kernel<<<(LIN + 3) / 4, 256, 0, stream>>>(dvf + val_elems, Wv, bv, val1);
        for (int b = 0; b < NB; b++) {
            attn16_kernel<<<NQ / 16, 256, 0, stream>>>(
                q_feat + (size_t)b * NQ * DM, refp + (size_t)b * NQ * 2,
                q_pos + (size_t)b * NQ * DM,
                Woap, bo, ba, Wout, bout, g1, b1,
                b == 0 ? val0 : val1, out + (size_t)b * NQ * DM);
        }
    } else {
        for (int b = 0; b < NB; b++) {
            val_proj_kernel<<<(LIN + 3) / 4, 256, 0, stream>>>(
                dvf + (size_t)b * val_elems, Wv, bv, val0);
            attn16_kernel<<<NQ / 16, 256, 0, stream>>>(
                q_feat + (size_t)b * NQ * DM, refp + (size_t)b * NQ * 2,
                q_pos + (size_t)b * NQ * DM,
                Woap, bo, ba, Wout, bout, g1, b1,
                val0, out + (size_t)b * NQ * DM);
        }
    }
    ffn_kernel<<<(NB * NQ) / 16, 256, 0, stream>>>(W1p, bff1, W2p, bff2, g2, b2, out);
}

// Round 9
// 324.139 us; speedup vs baseline: 1.6286x; 1.6286x over previous
//
#include <hip/hip_runtime.h>
#include <hip/hip_bf16.h>

#define NB 2
#define NQ 20000
#define DM 64
#define NH 8
#define NL 5
#define NP 4
#define LIN 45109
#define FFN 1024

typedef __attribute__((ext_vector_type(8))) short short8;
typedef __attribute__((ext_vector_type(4))) float f32x4;

__device__ __forceinline__ float b2f(const __hip_bfloat16 h) { return __bfloat162float(h); }

// ---- kernel 1: val[row,c] = (dvf_b[row,:] @ Wv + bv)[c], one batch, bf16 out ----
__global__ void val_proj_kernel(const float* __restrict__ dvf_b,
                                const float* __restrict__ Wv,
                                const float* __restrict__ bv,
                                __hip_bfloat16* __restrict__ val) {
    const int lane = threadIdx.x & 63;
    const int row = blockIdx.x * 4 + (threadIdx.x >> 6);
    if (row >= LIN) return;
    float mine = dvf_b[(size_t)row * DM + lane];
    float acc = bv[lane];
#pragma unroll 8
    for (int k = 0; k < DM; k++) {
        float vk = __shfl(mine, k, 64);
        acc = fmaf(vk, Wv[k * DM + lane], acc);
    }
    val[(size_t)row * DM + lane] = __float2bfloat16(acc);
}

// ---- kernel 2: pack W1/W2/[Wo|Wa] to bf16 MFMA B-fragment order ----
// B-frag 16x16x32: lane holds B[k=(lane>>4)*8+j][n=lane&15], j=0..7.
__global__ void pack_kernel(const float* __restrict__ W1, const float* __restrict__ W2,
                            const float* __restrict__ Wo, const float* __restrict__ Wa,
                            __hip_bfloat16* __restrict__ W1p, __hip_bfloat16* __restrict__ W2p,
                            __hip_bfloat16* __restrict__ Woap) {
    const int t = blockIdx.x * 256 + threadIdx.x;
    const int lane = t & 63;
    const int m = lane & 15, qd = lane >> 4;
    const int seg = t >> 6;
    if (seg < 128) {                  // W1 (64x1024): 64 ntiles x 2 kchunks
        const int nt = seg >> 1, kc = seg & 1;
        const int n = nt * 16 + m, kb = kc * 32 + qd * 8;
        __hip_bfloat16* dst = W1p + ((size_t)seg * 64 + lane) * 8;
#pragma unroll
        for (int j = 0; j < 8; j++) dst[j] = __float2bfloat16(W1[(size_t)(kb + j) * FFN + n]);
    } else if (seg < 256) {           // W2 (1024x64): 4 ntiles x 32 kchunks
        const int sl = seg - 128;
        const int nt = sl >> 5, kc = sl & 31;
        const int n = nt * 16 + m, kb = kc * 32 + qd * 8;
        __hip_bfloat16* dst = W2p + ((size_t)sl * 64 + lane) * 8;
#pragma unroll
        for (int j = 0; j < 8; j++) dst[j] = __float2bfloat16(W2[(size_t)(kb + j) * DM + n]);
    } else if (seg < 316) {           // [Wo|Wa] (64x480): 30 ntiles x 2 kchunks
        const int sl = seg - 256;
        const int nt = sl >> 1, kc = sl & 1;
        const int n = nt * 16 + m, kb = kc * 32 + qd * 8;
        __hip_bfloat16* dst = Woap + ((size_t)sl * 64 + lane) * 8;
#pragma unroll
        for (int j = 0; j < 8; j++) {
            const int k = kb + j;
            const float v = (n < 320) ? Wo[(size_t)k * 320 + n] : Wa[(size_t)k * 160 + (n - 320)];
            dst[j] = __float2bfloat16(v);
        }
    }
}

// ---- kernel 3: attn, 4 queries/block (wave = query); B via MFMA; C via descriptors ----
__global__ void __launch_bounds__(256)
attn4_kernel(const float* __restrict__ q_feat,
             const float* __restrict__ ref_pts,
             const float* __restrict__ q_pos,
             const __hip_bfloat16* __restrict__ Woap,
             const float* __restrict__ bo, const float* __restrict__ ba,
             const float* __restrict__ Wout, const float* __restrict__ bout,
             const float* __restrict__ g1, const float* __restrict__ b1,
             const __hip_bfloat16* __restrict__ val,
             float* __restrict__ xout) {
    __shared__ __align__(16) __hip_bfloat16 qb[16][72];   // A-frag; rows 4-15 zero
    __shared__ __align__(16) float offs[4][321];
    __shared__ __align__(16) float aws[4][161];
    __shared__ __align__(16) float refs[4][2];
    __shared__ __align__(16) int   dco[640][4];           // corner offsets (elements)
    __shared__ __align__(16) float dwt[640][4];           // bilinear weights * aV
    __shared__ __align__(16) float outv[4][64];

    const int tid = threadIdx.x;
    const int lane = tid & 63;
    const int w = tid >> 6;
    const int m16 = lane & 15, qd = lane >> 4;
    const int q0 = blockIdx.x * 4;
    const int qi = q0 + w;

    const int sz[NL]  = {184, 92, 46, 23, 12};
    const int lsi[NL] = {0, 33856, 42320, 44436, 44965};

    // ---- phase A: wave w owns query w ----
    const float qf = q_feat[(size_t)qi * DM + lane];
    const float qp = q_pos[(size_t)qi * DM + lane];
    qb[w][lane] = __float2bfloat16(qf + qp);
    for (int idx = tid; idx < 12 * 64; idx += 256)
        qb[4 + (idx >> 6)][idx & 63] = __float2bfloat16(0.f);
    if (tid < 8) refs[tid >> 1][tid & 1] = ref_pts[(size_t)(q0 + (tid >> 1)) * 2 + (tid & 1)];
    __syncthreads();

    // ---- phase B: [offs|aws] = q @ [Wo|Wa] + bias via MFMA (rows 0-3 valid) ----
    for (int nt = w; nt < 30; nt += 4) {
        f32x4 acc = {0.f, 0.f, 0.f, 0.f};
#pragma unroll
        for (int kc = 0; kc < 2; kc++) {
            const short8 a = *(const short8*)&qb[m16][kc * 32 + qd * 8];
            const short8 b = *(const short8*)(Woap + ((size_t)(nt * 2 + kc) * 64 + lane) * 8);
            acc = __builtin_amdgcn_mfma_f32_16x16x32_bf16(a, b, acc, 0, 0, 0);
        }
        if (qd == 0) {                       // rows 0..3 = queries 0..3
            const int n = nt * 16 + m16;
            if (n < 320) {
                const float bn = bo[n];
#pragma unroll
                for (int r = 0; r < 4; r++) offs[r][n] = acc[r] + bn;
            } else {
                const float bn = ba[n - 320];
#pragma unroll
                for (int r = 0; r < 4; r++) aws[r][n - 320] = acc[r] + bn;
            }
        }
    }
    __syncthreads();

    // ---- softmax per (query, head) over 20 ----
    if (tid < 32) {
        const int q = tid >> 3, h = tid & 7;
        float* p = &aws[q][h * 20];
        float mx = p[0];
        for (int j = 1; j < 20; j++) mx = fmaxf(mx, p[j]);
        float s = 0.f;
        for (int j = 0; j < 20; j++) { const float e = expf(p[j] - mx); p[j] = e; s += e; }
        const float inv = 1.f / s;
        for (int j = 0; j < 20; j++) p[j] *= inv;
    }
    __syncthreads();

    // ---- precompute sample descriptors: s = ((q*5+l)*4+p)*8 + h ----
    for (int s = tid; s < 640; s += 256) {
        const int h = s & 7;
        const int t2 = s >> 3;
        const int p = t2 & 3;
        const int t3 = t2 >> 2;           // q*5 + l
        const int l = t3 % 5;
        const int q = t3 / 5;
        const int Wl = sz[l];
        const float Wf = (float)Wl;
        const int st = lsi[l];
        const int c = ((h * 5 + l) * 4 + p) * 2;
        const float ox = offs[q][c], oy = offs[q][c + 1];
        const float fx = (refs[q][0] + ox / Wf) * Wf - 0.5f;
        const float fy = (refs[q][1] + oy / Wf) * Wf - 0.5f;
        const float x0f = floorf(fx), y0f = floorf(fy);
        const float wx = fx - x0f, wy = fy - y0f;
        const int x0 = (int)x0f, y0 = (int)y0f;
        const float aV = aws[q][h * 20 + l * 4 + p];
        const float w00 = (1.f - wx) * (1.f - wy) * aV;
        const float w10 = wx * (1.f - wy) * aV;
        const float w01 = (1.f - wx) * wy * aV;
        const float w11 = wx * wy * aV;
        const bool xin0 = (x0 >= 0) & (x0 < Wl), xin1 = (x0 + 1 >= 0) & (x0 + 1 < Wl);
        const bool yin0 = (y0 >= 0) & (y0 < Wl), yin1 = (y0 + 1 >= 0) & (y0 + 1 < Wl);
        int4 co; float4 wt;
        co.x = (xin0 && yin0) ? (st + y0 * Wl + x0) * DM : 0;
        wt.x = (xin0 && yin0) ? w00 : 0.f;
        co.y = (xin1 && yin0) ? (st + y0 * Wl + x0 + 1) * DM : 0;
        wt.y = (xin1 && yin0) ? w10 : 0.f;
        co.z = (xin0 && yin1) ? (st + (y0 + 1) * Wl + x0) * DM : 0;
        wt.z = (xin0 && yin1) ? w01 : 0.f;
        co.w = (xin1 && yin1) ? (st + (y0 + 1) * Wl + x0 + 1) * DM : 0;
        wt.w = (xin1 && yin1) ? w11 : 0.f;
        *(int4*)dco[s] = co;
        *(float4*)dwt[s] = wt;
    }
    __syncthreads();

    // ---- phase C: sampling, wave = query w; lane = h*8 + d ----
    {
        const int h = lane >> 3;
        const __hip_bfloat16* vbase = val + lane;
        float acc = 0.f;
#pragma unroll
        for (int l = 0; l < NL; l++) {
#pragma unroll
            for (int p = 0; p < NP; p++) {
                const int idx = ((w * 5 + l) * 4 + p) * 8 + h;
                const int4 co = *(const int4*)dco[idx];
                const float4 wt = *(const float4*)dwt[idx];
                acc = fmaf(wt.x, b2f(vbase[co.x]), acc);
                acc = fmaf(wt.y, b2f(vbase[co.y]), acc);
                acc = fmaf(wt.z, b2f(vbase[co.z]), acc);
                acc = fmaf(wt.w, b2f(vbase[co.w]), acc);
            }
        }
        outv[w][lane] = acc;   // wave-local write, wave-local read below
    }

    // ---- phase D: attn @ Wout + bout; residual; LN1; store x1 ----
    {
        float attn = bout[lane];
#pragma unroll 8
        for (int k = 0; k < DM; k++)
            attn = fmaf(outv[w][k], Wout[k * DM + lane], attn);
        const float xpre = qf + attn;
        float s = xpre, s2 = xpre * xpre;
#pragma unroll
        for (int o = 32; o >= 1; o >>= 1) {
            s += __shfl_xor(s, o, 64);
            s2 += __shfl_xor(s2, o, 64);
        }
        const float mean = s * (1.f / 64.f);
        const float var = s2 * (1.f / 64.f) - mean * mean;
        const float xn = (xpre - mean) * rsqrtf(var + 1e-5f);
        xout[(size_t)qi * DM + lane] = xn * g1[lane] + b1[lane];
    }
}

// ---- kernel 4: FFN via MFMA, 16 queries/block; in-place on io ----
__global__ void __launch_bounds__(256)
ffn_kernel(const __hip_bfloat16* __restrict__ W1p, const float* __restrict__ bff1,
           const __hip_bfloat16* __restrict__ W2p, const float* __restrict__ bff2,
           const float* __restrict__ g2, const float* __restrict__ b2,
           float* __restrict__ io) {
    __shared__ __align__(16) __hip_bfloat16 xb[16][72];
    __shared__ __align__(16) float xs[16][64];
    __shared__ __align__(16) __hip_bfloat16 hb[16][520];
    __shared__ __align__(16) float yr[16][64];

    const int tid = threadIdx.x;
    const int lane = tid & 63;
    const int w = tid >> 6;
    const int m16 = lane & 15, qd = lane >> 4;
    const int q0 = blockIdx.x * 16;

    {
        const int q = tid >> 4, i = tid & 15;
        const float4 v = *(const float4*)&io[(size_t)(q0 + q) * DM + i * 4];
        *(float4*)&xs[q][i * 4] = v;
        xb[q][i * 4 + 0] = __float2bfloat16(v.x);
        xb[q][i * 4 + 1] = __float2bfloat16(v.y);
        xb[q][i * 4 + 2] = __float2bfloat16(v.z);
        xb[q][i * 4 + 3] = __float2bfloat16(v.w);
    }
    __syncthreads();

    f32x4 yacc = {0.f, 0.f, 0.f, 0.f};
#pragma unroll
    for (int half = 0; half < 2; half++) {
#pragma unroll 2
        for (int ti = 0; ti < 8; ti++) {
            const int nt = half * 32 + w + ti * 4;
            f32x4 acc = {0.f, 0.f, 0.f, 0.f};
#pragma unroll
            for (int kc = 0; kc < 2; kc++) {
                const short8 a = *(const short8*)&xb[m16][kc * 32 + qd * 8];
                const short8 b = *(const short8*)(W1p + ((size_t)(nt * 2 + kc) * 64 + lane) * 8);
                acc = __builtin_amdgcn_mfma_f32_16x16x32_bf16(a, b, acc, 0, 0, 0);
            }
            const int ncol = (nt - half * 32) * 16 + m16;
            const float bn = bff1[nt * 16 + m16];
#pragma unroll
            for (int r = 0; r < 4; r++)
                hb[qd * 4 + r][ncol] = __float2bfloat16(fmaxf(acc[r] + bn, 0.f));
        }
        __syncthreads();
#pragma unroll 4
        for (int kc2 = 0; kc2 < 16; kc2++) {
            const short8 a = *(const short8*)&hb[m16][kc2 * 32 + qd * 8];
            const short8 b = *(const short8*)(W2p + ((size_t)(w * 32 + half * 16 + kc2) * 64 + lane) * 8);
            yacc = __builtin_amdgcn_mfma_f32_16x16x32_bf16(a, b, yacc, 0, 0, 0);
        }
        __syncthreads();
    }

    {
        const int n = w * 16 + m16;
        const float bn = bff2[n];
#pragma unroll
        for (int r = 0; r < 4; r++) {
            const int mm = qd * 4 + r;
            yr[mm][n] = yacc[r] + bn + xs[mm][n];
        }
    }
    __syncthreads();

    {
        const int q = tid >> 4, i = tid & 15;
        const float4 v = *(const float4*)&yr[q][i * 4];
        float s = v.x + v.y + v.z + v.w;
        float s2 = v.x * v.x + v.y * v.y + v.z * v.z + v.w * v.w;
#pragma unroll
        for (int o = 8; o >= 1; o >>= 1) { s += __shfl_xor(s, o, 64); s2 += __shfl_xor(s2, o, 64); }
        const float mean = s * (1.f / 64.f);
        const float var = s2 * (1.f / 64.f) - mean * mean;
        const float rstd = rsqrtf(var + 1e-5f);
        const float4 g = *(const float4*)&g2[i * 4];
        const float4 bb = *(const float4*)&b2[i * 4];
        float4 o;
        o.x = (v.x - mean) * rstd * g.x + bb.x;
        o.y = (v.y - mean) * rstd * g.y + bb.y;
        o.z = (v.z - mean) * rstd * g.z + bb.z;
        o.w = (v.w - mean) * rstd * g.w + bb.w;
        *(float4*)&io[(size_t)(q0 + q) * DM + i * 4] = o;
    }
}

extern "C" void kernel_launch(void* const* d_in, const int* in_sizes, int n_in,
                              void* d_out, int out_size, void* d_ws, size_t ws_size,
                              hipStream_t stream) {
    const int B0 = (in_sizes[4] >= 4096) ? 4 : 6;   // int side-inputs present -> 6
    const float* q_feat = (const float*)d_in[0];
    const float* dvf    = (const float*)d_in[1];
    const float* refp   = (const float*)d_in[2];
    const float* q_pos  = (const float*)d_in[3];
    const float* Wv   = (const float*)d_in[B0 + 0];
    const float* bv   = (const float*)d_in[B0 + 1];
    const float* Wo   = (const float*)d_in[B0 + 2];
    const float* bo   = (const float*)d_in[B0 + 3];
    const float* Wa   = (const float*)d_in[B0 + 4];
    const float* ba   = (const float*)d_in[B0 + 5];
    const float* Wout = (const float*)d_in[B0 + 6];
    const float* bout = (const float*)d_in[B0 + 7];
    const float* g1   = (const float*)d_in[B0 + 8];
    const float* b1   = (const float*)d_in[B0 + 9];
    const float* W1   = (const float*)d_in[B0 + 10];
    const float* bff1 = (const float*)d_in[B0 + 11];
    const float* W2   = (const float*)d_in[B0 + 12];
    const float* bff2 = (const float*)d_in[B0 + 13];
    const float* g2   = (const float*)d_in[B0 + 14];
    const float* b2   = (const float*)d_in[B0 + 15];
    float* out = (float*)d_out;

    const size_t val_elems = (size_t)LIN * DM;
    const size_t pack_elems = (size_t)(128 + 128 + 60) * 64 * 8;   // 161792 bf16
    const bool dbuf = ws_size >= (pack_elems + 2 * val_elems) * sizeof(__hip_bfloat16);

    __hip_bfloat16* W1p = (__hip_bfloat16*)d_ws;
    __hip_bfloat16* W2p = W1p + (size_t)128 * 64 * 8;
    __hip_bfloat16* Woap = W2p + (size_t)128 * 64 * 8;
    __hip_bfloat16* val0 = W1p + pack_elems;
    __hip_bfloat16* val1 = dbuf ? val0 + val_elems : val0;

    pack_kernel<<<79, 256, 0, stream>>>(W1, W2, Wo, Wa, W1p, W2p, Woap);

    if (dbuf) {
        val_proj_kernel<<<(LIN + 3) / 4, 256, 0, stream>>>(dvf, Wv, bv, val0);
        val_proj_kernel<<<(LIN + 3) / 4, 256, 0, stream>>>(dvf + val_elems, Wv, bv, val1);
        for (int b = 0; b < NB; b++) {
            attn4_kernel<<<NQ / 4, 256, 0, stream>>>(
                q_feat + (size_t)b * NQ * DM, refp + (size_t)b * NQ * 2,
                q_pos + (size_t)b * NQ * DM,
                Woap, bo, ba, Wout, bout, g1, b1,
                b == 0 ? val0 : val1, out + (size_t)b * NQ * DM);
        }
    } else {
        for (int b = 0; b < NB; b++) {
            val_proj_kernel<<<(LIN + 3) / 4, 256, 0, stream>>>(
                dvf + (size_t)b * val_elems, Wv, bv, val0);
            attn4_kernel<<<NQ / 4, 256, 0, stream>>>(
                q_feat + (size_t)b * NQ * DM, refp + (size_t)b * NQ * 2,
                q_pos + (size_t)b * NQ * DM,
                Woap, bo, ba, Wout, bout, g1, b1,
                val0, out + (size_t)b * NQ * DM);
        }
    }
    ffn_kernel<<<(NB * NQ) / 16, 256, 0, stream>>>(W1p, bff1, W2p, bff2, g2, b2, out);
}